// Round 2
// baseline (804.933 us; speedup 1.0000x reference)
//
#include <hip/hip_runtime.h>
#include <hip/hip_bf16.h>

typedef __attribute__((ext_vector_type(8))) short s16x8;
typedef __attribute__((ext_vector_type(4))) float f32x4;

#define HC 8        // edge chunks (shared by hist + scatter)
#define RBH 12500   // hist bins per range   (50 KB LDS)
#define RBS 6250    // scatter cursors per range (25 KB + 25 KB dis)

static __device__ __forceinline__ unsigned short f2bf(float f) {
    unsigned int u = __float_as_uint(f);
    unsigned int r = (u + 0x7FFFu + ((u >> 16) & 1u)) >> 16;
    return (unsigned short)r;
}
static __device__ __forceinline__ float bf2f(unsigned short u) {
    return __uint_as_float(((unsigned int)u) << 16);
}

// ---- partial histograms, zero global atomics ----
// grid = 2 jobs * HR ranges * HC chunks. job0: src -> deg partials, job1: dst -> cnt partials
// partials[(job*HC + c)*N + n]
__global__ void k_hist(const int* __restrict__ eidx, int* __restrict__ partials,
                       int N, int E, int HR) {
    __shared__ int h[RBH];
    int b = blockIdx.x;
    int job = b / (HR * HC);
    int rc = b % (HR * HC);
    int r = rc / HC, c = rc % HC;
    int lo = r * RBH;
    int nb = min(RBH, N - lo);
    if (nb <= 0) return;
    for (int i = threadIdx.x; i < nb; i += 256) h[i] = 0;
    __syncthreads();
    const int* vals = eidx + (size_t)job * E;
    int e0 = (int)((long long)E * c / HC);
    int e1 = (int)((long long)E * (c + 1) / HC);
    for (int e = e0 + threadIdx.x; e < e1; e += 256) {
        unsigned rel = (unsigned)(vals[e] - lo);
        if (rel < (unsigned)nb) atomicAdd(&h[rel], 1);
    }
    __syncthreads();
    int* outp = partials + ((size_t)(job * HC + c)) * N + lo;
    for (int i = threadIdx.x; i < nb; i += 256) outp[i] = h[i];
}

// ---- combine partials -> dis (rsqrt of src-degree) and cnt (dst histogram) ----
__global__ void k_reduce(const int* __restrict__ partials, float* __restrict__ dis,
                         int* __restrict__ cnt, int N) {
    int n = blockIdx.x * blockDim.x + threadIdx.x;
    if (n >= N) return;
    int dsum = 0, csum = 0;
#pragma unroll
    for (int c = 0; c < HC; ++c) {
        dsum += partials[(size_t)c * N + n];
        csum += partials[(size_t)(HC + c) * N + n];
    }
    dis[n] = dsum > 0 ? rsqrtf((float)dsum) : 0.f;
    cnt[n] = csum;
}

// ---- 3-kernel exclusive scan of cnt -> rowptr ----
__global__ void k_scan1(const int* __restrict__ cnt, int* __restrict__ incl,
                        int* __restrict__ bsum, int N) {
    __shared__ int sm[1024];
    int t = threadIdx.x;
    int i = blockIdx.x * 1024 + t;
    sm[t] = (i < N) ? cnt[i] : 0;
    __syncthreads();
    for (int off = 1; off < 1024; off <<= 1) {
        int add = (t >= off) ? sm[t - off] : 0;
        __syncthreads();
        sm[t] += add;
        __syncthreads();
    }
    if (i < N) incl[i] = sm[t];
    if (t == 1023) bsum[blockIdx.x] = sm[1023];
}

__global__ void k_scan2(const int* __restrict__ bsum, int* __restrict__ boff,
                        int nb, int* __restrict__ rowptr, int N) {
    if (threadIdx.x == 0 && blockIdx.x == 0) {
        int run = 0;
        for (int b = 0; b < nb; ++b) { boff[b] = run; run += bsum[b]; }
        rowptr[N] = run;
    }
}

__global__ void k_scan3(const int* __restrict__ cnt, const int* __restrict__ boff,
                        int* __restrict__ rowptr, int N) {
    int i = blockIdx.x * 1024 + threadIdx.x;
    if (i < N) rowptr[i] = rowptr[i] - cnt[i] + boff[blockIdx.x];  // inclusive -> exclusive
}

// ---- bucket edges by dst, LDS cursors only (no global atomics) ----
// grid = SR ranges * HC chunks; per-(dst,chunk) start = rowptr[d] + sum_{c'<c} partial_dst[c'][d]
__global__ __launch_bounds__(1024) void k_scatter(
        const int* __restrict__ src, const int* __restrict__ dst,
        const float* __restrict__ dis, const int* __restrict__ rowptr,
        const int* __restrict__ pdst, int2* __restrict__ edat, int N, int E) {
    __shared__ int cur[RBS];
    __shared__ float dl[RBS];
    int r = blockIdx.x / HC, c = blockIdx.x % HC;
    int lo = r * RBS;
    int nb = min(RBS, N - lo);
    if (nb <= 0) return;
    for (int i = threadIdx.x; i < nb; i += 1024) {
        int base = rowptr[lo + i];
        for (int cc = 0; cc < c; ++cc) base += pdst[(size_t)cc * N + lo + i];
        cur[i] = base;
        dl[i] = dis[lo + i];
    }
    __syncthreads();
    int e0 = (int)((long long)E * c / HC);
    int e1 = (int)((long long)E * (c + 1) / HC);
    for (int e = e0 + threadIdx.x; e < e1; e += 1024) {
        int d = dst[e];
        unsigned rel = (unsigned)(d - lo);
        if (rel < (unsigned)nb) {
            int s = src[e];
            int p = atomicAdd(&cur[rel], 1);
            edat[p] = make_int2(s, __float_as_int(-dis[s] * dl[rel]));
        }
    }
}

// ---- x -> bf16 copy (T_0 for the GEMM) ----
__global__ void k_xb(const float* __restrict__ x, unsigned short* __restrict__ tb0, int n4) {
    int i = blockIdx.x * blockDim.x + threadIdx.x;
    if (i < n4) {
        float4 v = ((const float4*)x)[i];
        ushort4 o;
        o.x = f2bf(v.x); o.y = f2bf(v.y); o.z = f2bf(v.z); o.w = f2bf(v.w);
        ((ushort4*)tb0)[i] = o;
    }
}

// ---- W [K][64][64] fp32 -> Wt bf16 transposed (A-operand friendly) ----
__global__ void k_wt(const float* __restrict__ W, unsigned short* __restrict__ wt,
                     int total, int KI) {
    int t = blockIdx.x * blockDim.x + threadIdx.x;
    if (t < total) {
        float v = W[t];
        int k = t >> 12;
        int r = t & 4095;
        int i = r >> 6;
        int j = r & 63;
        wt[(size_t)j * KI + (k << 6) + i] = f2bf(v);
    }
}

// ---- one Chebyshev propagation: Tnew = scale*(L_hat @ Told) + beta*Tprev_bf16 ----
// one wave per dst node, lane = feature; CSR gather, no atomics; fp32 gathers/acc
__global__ void k_prop(const float* __restrict__ Told, const unsigned short* __restrict__ Tprev,
                       float* __restrict__ Tnew, unsigned short* __restrict__ Tbn,
                       const int* __restrict__ rowptr, const int2* __restrict__ edat,
                       int N, float scale, float beta) {
    int gt = blockIdx.x * blockDim.x + threadIdx.x;
    int wid = gt >> 6;
    int lane = gt & 63;
    if (wid >= N) return;
    int rs = rowptr[wid], re = rowptr[wid + 1];
    float acc = 0.f;
    int e = rs;
    for (; e + 4 <= re; e += 4) {
        int2 v0 = edat[e], v1 = edat[e + 1], v2 = edat[e + 2], v3 = edat[e + 3];
        float t0 = Told[(size_t)v0.x * 64 + lane];
        float t1 = Told[(size_t)v1.x * 64 + lane];
        float t2 = Told[(size_t)v2.x * 64 + lane];
        float t3 = Told[(size_t)v3.x * 64 + lane];
        acc = fmaf(__int_as_float(v0.y), t0, acc);
        acc = fmaf(__int_as_float(v1.y), t1, acc);
        acc = fmaf(__int_as_float(v2.y), t2, acc);
        acc = fmaf(__int_as_float(v3.y), t3, acc);
    }
    for (; e < re; ++e) {
        int2 v = edat[e];
        acc = fmaf(__int_as_float(v.y), Told[(size_t)v.x * 64 + lane], acc);
    }
    float r = scale * acc;
    size_t idx = (size_t)wid * 64 + lane;
    if (beta != 0.f) r = fmaf(beta, bf2f(Tprev[idx]), r);
    Tnew[idx] = r;
    Tbn[idx] = f2bf(r);
}

// ---- out = relu( sum_k T_k @ W_k + bias ) via D = W^T . T^T (MFMA 16x16x32 bf16) ----
template <int KS>
__global__ __launch_bounds__(256) void k_gemm(const unsigned short* __restrict__ tb,
                                              const unsigned short* __restrict__ wt,
                                              const float* __restrict__ bias,
                                              float* __restrict__ out,
                                              int N, int NF) {
    int lane = threadIdx.x & 63;
    int w = threadIdx.x >> 6;
    int l16 = lane & 15;
    int quad = lane >> 4;
    const int KI = KS * 32;

    s16x8 afr[KS];
    {
        const unsigned short* wrow = wt + (size_t)(w * 16 + l16) * KI + quad * 8;
#pragma unroll
        for (int ks = 0; ks < KS; ++ks)
            afr[ks] = *reinterpret_cast<const s16x8*>(wrow + ks * 32);
    }
    f32x4 bias4 = *reinterpret_cast<const f32x4*>(bias + w * 16 + quad * 4);

    int ntiles = N >> 4;
    for (int t = blockIdx.x; t < ntiles; t += gridDim.x) {
        const unsigned short* bbase = tb + (size_t)(t * 16 + l16) * 64 + quad * 8;
        f32x4 acc = {0.f, 0.f, 0.f, 0.f};
#pragma unroll
        for (int ks = 0; ks < KS; ++ks) {
            s16x8 bf = *reinterpret_cast<const s16x8*>(
                bbase + (size_t)(ks >> 1) * NF + (ks & 1) * 32);
            acc = __builtin_amdgcn_mfma_f32_16x16x32_bf16(afr[ks], bf, acc, 0, 0, 0);
        }
        float* orow = out + (size_t)(t * 16 + l16) * 64 + w * 16 + quad * 4;
        f32x4 r;
#pragma unroll
        for (int q = 0; q < 4; ++q) {
            float v = acc[q] + bias4[q];
            r[q] = v > 0.f ? v : 0.f;
        }
        *reinterpret_cast<f32x4*>(orow) = r;
    }
}

extern "C" void kernel_launch(void* const* d_in, const int* in_sizes, int n_in,
                              void* d_out, int out_size, void* d_ws, size_t ws_size,
                              hipStream_t stream) {
    const float* x    = (const float*)d_in[0];
    const int*   eidx = (const int*)d_in[1];
    const float* W    = (const float*)d_in[2];
    const float* bias = (const float*)d_in[3];
    float* out = (float*)d_out;

    const int NF = in_sizes[0];       // N*64
    const int N  = NF / 64;
    const int E  = in_sizes[1] / 2;
    const int K  = in_sizes[2] / 4096;

    const int* src = eidx;
    const int* dst = eidx + E;

    // workspace layout (~170 MB)
    char* ws = (char*)d_ws;
    size_t off = 0;
    auto alloc = [&](size_t bytes) -> char* {
        char* p = ws + off;
        off = (off + bytes + 255) & ~(size_t)255;
        return p;
    };
    float* Tf[2];
    for (int i = 0; i < 2; ++i) Tf[i] = (float*)alloc((size_t)NF * 4);   // fp32 recursion (ping-pong)
    unsigned short* Tb = (unsigned short*)alloc((size_t)K * NF * 2);     // bf16 copies T_0..T_{K-1}
    unsigned short* Wt = (unsigned short*)alloc((size_t)64 * K * 64 * 2);
    int2*  edat   = (int2*)alloc((size_t)E * 8);
    int*   rowptr = (int*)alloc((size_t)(N + 1) * 4);
    int*   cnt    = (int*)alloc((size_t)N * 4);
    int*   partials = (int*)alloc((size_t)2 * HC * N * 4);
    float* dis  = (float*)alloc((size_t)N * 4);
    int*   bsum = (int*)alloc(1024);
    int*   boff = (int*)alloc(1024);
    (void)ws_size; (void)n_in; (void)out_size;

    int HR = (N + RBH - 1) / RBH;   // hist ranges (8 for N=100k)
    int SR = (N + RBS - 1) / RBS;   // scatter ranges (16)

    k_hist<<<2 * HR * HC, 256, 0, stream>>>(eidx, partials, N, E, HR);
    k_reduce<<<(N + 255) / 256, 256, 0, stream>>>(partials, dis, cnt, N);
    int nb = (N + 1023) / 1024;
    k_scan1<<<nb, 1024, 0, stream>>>(cnt, rowptr, bsum, N);
    k_scan2<<<1, 64, 0, stream>>>(bsum, boff, nb, rowptr, N);
    k_scan3<<<nb, 1024, 0, stream>>>(cnt, boff, rowptr, N);
    k_scatter<<<SR * HC, 1024, 0, stream>>>(src, dst, dis, rowptr,
                                            partials + (size_t)HC * N, edat, N, E);
    k_xb<<<(NF / 4 + 255) / 256, 256, 0, stream>>>(x, Tb, NF / 4);
    k_wt<<<(K * 4096 + 255) / 256, 256, 0, stream>>>(W, Wt, K * 4096, K * 64);

    // Chebyshev recursion: T1 = L x; Tk = 2 L T_{k-1} - T_{k-2}
    const float* Tm1 = x;
    for (int p = 1; p < K; ++p) {
        float* Tn = Tf[(p - 1) & 1];
        float scale = (p == 1) ? 1.f : 2.f;
        float beta  = (p == 1) ? 0.f : -1.f;
        const unsigned short* Tprev = Tb + (size_t)(p >= 2 ? p - 2 : 0) * NF;
        k_prop<<<(N * 64 + 255) / 256, 256, 0, stream>>>(
            Tm1, Tprev, Tn, Tb + (size_t)p * NF, rowptr, edat, N, scale, beta);
        Tm1 = Tn;
    }

    if (K == 8)      k_gemm<16><<<1024, 256, 0, stream>>>(Tb, Wt, bias, out, N, NF);
    else if (K == 4) k_gemm<8><<<1024, 256, 0, stream>>>(Tb, Wt, bias, out, N, NF);
    else if (K == 2) k_gemm<4><<<1024, 256, 0, stream>>>(Tb, Wt, bias, out, N, NF);
    else if (K == 1) k_gemm<2><<<1024, 256, 0, stream>>>(Tb, Wt, bias, out, N, NF);
}

// Round 3
// 581.971 us; speedup vs baseline: 1.3831x; 1.3831x over previous
//
#include <hip/hip_runtime.h>
#include <hip/hip_bf16.h>

typedef __attribute__((ext_vector_type(8))) short s16x8;
typedef __attribute__((ext_vector_type(4))) float f32x4;

#define HC 48       // edge chunks (hist + scatter) -> grids of 768 = 256 CU x 3 blocks
#define RBH 12500   // hist bins per range   (50 KB LDS, 8 ranges for N=100k)
#define RBS 6250    // scatter cursors per range (25 KB cur + 25 KB dis, 16 ranges)

static __device__ __forceinline__ unsigned short f2bf(float f) {
    unsigned int u = __float_as_uint(f);
    unsigned int r = (u + 0x7FFFu + ((u >> 16) & 1u)) >> 16;
    return (unsigned short)r;
}

// ---- partial histograms, zero global atomics ----
// grid = 2 jobs * HR * HC. job0: src -> deg partials, job1: dst -> cnt partials
// partials[(job*HC + c)*N + n]
__global__ void k_hist(const int* __restrict__ eidx, int* __restrict__ partials,
                       int N, int E, int HR) {
    __shared__ int h[RBH];
    int b = blockIdx.x;
    int job = b / (HR * HC);
    int rc = b % (HR * HC);
    int r = rc / HC, c = rc % HC;
    int lo = r * RBH;
    int nb = min(RBH, N - lo);
    if (nb <= 0) return;
    for (int i = threadIdx.x; i < nb; i += 256) h[i] = 0;
    __syncthreads();
    const int* vals = eidx + (size_t)job * E;
    int e0 = (int)((long long)E * c / HC);
    int e1 = (int)((long long)E * (c + 1) / HC);
    for (int e = e0 + threadIdx.x; e < e1; e += 256) {
        unsigned rel = (unsigned)(vals[e] - lo);
        if (rel < (unsigned)nb) atomicAdd(&h[rel], 1);
    }
    __syncthreads();
    int* outp = partials + ((size_t)(job * HC + c)) * N + lo;
    for (int i = threadIdx.x; i < nb; i += 256) outp[i] = h[i];
}

// ---- combine partials -> dis (rsqrt of src-degree) and cnt (dst histogram) ----
__global__ void k_reduce(const int* __restrict__ partials, float* __restrict__ dis,
                         int* __restrict__ cnt, int N) {
    int n = blockIdx.x * blockDim.x + threadIdx.x;
    if (n >= N) return;
    int dsum = 0, csum = 0;
    for (int c = 0; c < HC; ++c) {
        dsum += partials[(size_t)c * N + n];
        csum += partials[(size_t)(HC + c) * N + n];
    }
    dis[n] = dsum > 0 ? rsqrtf((float)dsum) : 0.f;
    cnt[n] = csum;
}

// ---- 3-kernel exclusive scan of cnt -> rowptr ----
__global__ void k_scan1(const int* __restrict__ cnt, int* __restrict__ incl,
                        int* __restrict__ bsum, int N) {
    __shared__ int sm[1024];
    int t = threadIdx.x;
    int i = blockIdx.x * 1024 + t;
    sm[t] = (i < N) ? cnt[i] : 0;
    __syncthreads();
    for (int off = 1; off < 1024; off <<= 1) {
        int add = (t >= off) ? sm[t - off] : 0;
        __syncthreads();
        sm[t] += add;
        __syncthreads();
    }
    if (i < N) incl[i] = sm[t];
    if (t == 1023) bsum[blockIdx.x] = sm[1023];
}

__global__ void k_scan2(const int* __restrict__ bsum, int* __restrict__ boff,
                        int nb, int* __restrict__ rowptr, int N) {
    if (threadIdx.x == 0 && blockIdx.x == 0) {
        int run = 0;
        for (int b = 0; b < nb; ++b) { boff[b] = run; run += bsum[b]; }
        rowptr[N] = run;
    }
}

__global__ void k_scan3(const int* __restrict__ cnt, const int* __restrict__ boff,
                        int* __restrict__ rowptr, int N) {
    int i = blockIdx.x * 1024 + threadIdx.x;
    if (i < N) rowptr[i] = rowptr[i] - cnt[i] + boff[blockIdx.x];  // inclusive -> exclusive
}

// ---- in-place 2D prefix over dst partials: pdst[c][n] -> rowptr[n] + sum_{c'<c} pdst[c'][n]
__global__ void k_csum(int* __restrict__ pdst, const int* __restrict__ rowptr, int N) {
    int n = blockIdx.x * blockDim.x + threadIdx.x;
    if (n >= N) return;
    int run = rowptr[n];
    for (int c = 0; c < HC; ++c) {
        size_t idx = (size_t)c * N + n;
        int t = pdst[idx];
        pdst[idx] = run;
        run += t;
    }
}

// ---- bucket edges by dst, LDS cursors only (no global atomics) ----
__global__ __launch_bounds__(256) void k_scatter(
        const int* __restrict__ src, const int* __restrict__ dst,
        const float* __restrict__ dis, const int* __restrict__ cbase,
        int2* __restrict__ edat, int N, int E) {
    __shared__ int cur[RBS];
    __shared__ float dl[RBS];
    int r = blockIdx.x / HC, c = blockIdx.x % HC;
    int lo = r * RBS;
    int nb = min(RBS, N - lo);
    if (nb <= 0) return;
    for (int i = threadIdx.x; i < nb; i += 256) {
        cur[i] = cbase[(size_t)c * N + lo + i];
        dl[i] = dis[lo + i];
    }
    __syncthreads();
    int e0 = (int)((long long)E * c / HC);
    int e1 = (int)((long long)E * (c + 1) / HC);
    for (int e = e0 + threadIdx.x; e < e1; e += 256) {
        int d = dst[e];
        unsigned rel = (unsigned)(d - lo);
        if (rel < (unsigned)nb) {
            int s = src[e];
            int p = atomicAdd(&cur[rel], 1);
            edat[p] = make_int2(s, __float_as_int(-dis[s] * dl[rel]));
        }
    }
}

// ---- x -> bf16 copy (T_0) ----
__global__ void k_xb(const float* __restrict__ x, unsigned short* __restrict__ tb0, int n4) {
    int i = blockIdx.x * blockDim.x + threadIdx.x;
    if (i < n4) {
        float4 v = ((const float4*)x)[i];
        ushort4 o;
        o.x = f2bf(v.x); o.y = f2bf(v.y); o.z = f2bf(v.z); o.w = f2bf(v.w);
        ((ushort4*)tb0)[i] = o;
    }
}

// ---- W [K][64][64] fp32 -> Wt bf16 transposed (A-operand friendly) ----
__global__ void k_wt(const float* __restrict__ W, unsigned short* __restrict__ wt,
                     int total, int KI) {
    int t = blockIdx.x * blockDim.x + threadIdx.x;
    if (t < total) {
        float v = W[t];
        int k = t >> 12;
        int r = t & 4095;
        int i = r >> 6;
        int j = r & 63;
        wt[(size_t)j * KI + (k << 6) + i] = f2bf(v);
    }
}

// ---- one Chebyshev propagation, all-bf16 state:
//   Tout = scale*(L_hat @ Tin) + beta*Tm2   (compute fp32, storage bf16)
// one wave per dst node; lane l=lane&31 holds feature pair (2l, 2l+1) as one dword;
// half-wave h=lane>>5 processes edge e+h -> 2 edges per load instruction.
__global__ void k_prop(const unsigned short* __restrict__ Tin,
                       const unsigned short* __restrict__ Tm2,
                       unsigned short* __restrict__ Tout,
                       const int* __restrict__ rowptr, const int2* __restrict__ edat,
                       int N, float scale, float beta) {
    int gt = blockIdx.x * blockDim.x + threadIdx.x;
    int wid = gt >> 6;
    if (wid >= N) return;
    int lane = gt & 63;
    int h = lane >> 5;
    int l = lane & 31;
    int rs = rowptr[wid], re = rowptr[wid + 1];
    float ax = 0.f, ay = 0.f;
    int e = rs;
    for (; e + 4 <= re; e += 4) {
        int2 e0 = edat[e + h];
        int2 e1 = edat[e + 2 + h];
        unsigned t0 = *(const unsigned*)(Tin + ((size_t)e0.x << 6) + (l << 1));
        unsigned t1 = *(const unsigned*)(Tin + ((size_t)e1.x << 6) + (l << 1));
        float w0 = __int_as_float(e0.y), w1 = __int_as_float(e1.y);
        ax = fmaf(w0, __uint_as_float(t0 << 16), ax);
        ay = fmaf(w0, __uint_as_float(t0 & 0xffff0000u), ay);
        ax = fmaf(w1, __uint_as_float(t1 << 16), ax);
        ay = fmaf(w1, __uint_as_float(t1 & 0xffff0000u), ay);
    }
    for (; e < re; e += 2) {
        int ee = e + h;
        bool live = ee < re;
        int2 ed = edat[live ? ee : rs];
        float w = live ? __int_as_float(ed.y) : 0.f;
        unsigned tv = *(const unsigned*)(Tin + ((size_t)ed.x << 6) + (l << 1));
        ax = fmaf(w, __uint_as_float(tv << 16), ax);
        ay = fmaf(w, __uint_as_float(tv & 0xffff0000u), ay);
    }
    ax += __shfl_xor(ax, 32);
    ay += __shfl_xor(ay, 32);
    float rx = scale * ax, ry = scale * ay;
    if (beta != 0.f) {
        unsigned pv = *(const unsigned*)(Tm2 + ((size_t)wid << 6) + (l << 1));
        rx = fmaf(beta, __uint_as_float(pv << 16), rx);
        ry = fmaf(beta, __uint_as_float(pv & 0xffff0000u), ry);
    }
    if (h == 0) {
        unsigned ov = ((unsigned)f2bf(rx)) | (((unsigned)f2bf(ry)) << 16);
        *(unsigned*)(Tout + ((size_t)wid << 6) + (l << 1)) = ov;
    }
}

// ---- out = relu( sum_k T_k @ W_k + bias ) via D = W^T . T^T (MFMA 16x16x32 bf16) ----
template <int KS>
__global__ __launch_bounds__(256) void k_gemm(const unsigned short* __restrict__ tb,
                                              const unsigned short* __restrict__ wt,
                                              const float* __restrict__ bias,
                                              float* __restrict__ out,
                                              int N, int NF) {
    int lane = threadIdx.x & 63;
    int w = threadIdx.x >> 6;
    int l16 = lane & 15;
    int quad = lane >> 4;
    const int KI = KS * 32;

    s16x8 afr[KS];
    {
        const unsigned short* wrow = wt + (size_t)(w * 16 + l16) * KI + quad * 8;
#pragma unroll
        for (int ks = 0; ks < KS; ++ks)
            afr[ks] = *reinterpret_cast<const s16x8*>(wrow + ks * 32);
    }
    f32x4 bias4 = *reinterpret_cast<const f32x4*>(bias + w * 16 + quad * 4);

    int ntiles = N >> 4;
    for (int t = blockIdx.x; t < ntiles; t += gridDim.x) {
        const unsigned short* bbase = tb + (size_t)(t * 16 + l16) * 64 + quad * 8;
        f32x4 acc = {0.f, 0.f, 0.f, 0.f};
#pragma unroll
        for (int ks = 0; ks < KS; ++ks) {
            s16x8 bf = *reinterpret_cast<const s16x8*>(
                bbase + (size_t)(ks >> 1) * NF + (ks & 1) * 32);
            acc = __builtin_amdgcn_mfma_f32_16x16x32_bf16(afr[ks], bf, acc, 0, 0, 0);
        }
        float* orow = out + (size_t)(t * 16 + l16) * 64 + w * 16 + quad * 4;
        f32x4 r;
#pragma unroll
        for (int q = 0; q < 4; ++q) {
            float v = acc[q] + bias4[q];
            r[q] = v > 0.f ? v : 0.f;
        }
        *reinterpret_cast<f32x4*>(orow) = r;
    }
}

extern "C" void kernel_launch(void* const* d_in, const int* in_sizes, int n_in,
                              void* d_out, int out_size, void* d_ws, size_t ws_size,
                              hipStream_t stream) {
    const float* x    = (const float*)d_in[0];
    const int*   eidx = (const int*)d_in[1];
    const float* W    = (const float*)d_in[2];
    const float* bias = (const float*)d_in[3];
    float* out = (float*)d_out;

    const int NF = in_sizes[0];       // N*64
    const int N  = NF / 64;
    const int E  = in_sizes[1] / 2;
    const int K  = in_sizes[2] / 4096;

    const int* src = eidx;
    const int* dst = eidx + E;

    // workspace (~150 MB)
    char* ws = (char*)d_ws;
    size_t off = 0;
    auto alloc = [&](size_t bytes) -> char* {
        char* p = ws + off;
        off = (off + bytes + 255) & ~(size_t)255;
        return p;
    };
    unsigned short* Tb = (unsigned short*)alloc((size_t)K * NF * 2);   // bf16 T_0..T_{K-1}
    unsigned short* Wt = (unsigned short*)alloc((size_t)64 * K * 64 * 2);
    int2*  edat   = (int2*)alloc((size_t)E * 8);
    int*   rowptr = (int*)alloc((size_t)(N + 1) * 4);
    int*   cnt    = (int*)alloc((size_t)N * 4);
    int*   partials = (int*)alloc((size_t)2 * HC * N * 4);
    float* dis  = (float*)alloc((size_t)N * 4);
    int*   bsum = (int*)alloc(1024);
    int*   boff = (int*)alloc(1024);
    (void)ws_size; (void)n_in; (void)out_size;

    int HR = (N + RBH - 1) / RBH;   // 8
    int SR = (N + RBS - 1) / RBS;   // 16
    int* pdst = partials + (size_t)HC * N;

    k_hist<<<2 * HR * HC, 256, 0, stream>>>(eidx, partials, N, E, HR);
    k_reduce<<<(N + 255) / 256, 256, 0, stream>>>(partials, dis, cnt, N);
    int nb = (N + 1023) / 1024;
    k_scan1<<<nb, 1024, 0, stream>>>(cnt, rowptr, bsum, N);
    k_scan2<<<1, 64, 0, stream>>>(bsum, boff, nb, rowptr, N);
    k_scan3<<<nb, 1024, 0, stream>>>(cnt, boff, rowptr, N);
    k_csum<<<(N + 255) / 256, 256, 0, stream>>>(pdst, rowptr, N);
    k_scatter<<<SR * HC, 256, 0, stream>>>(src, dst, dis, pdst, edat, N, E);
    k_xb<<<(NF / 4 + 255) / 256, 256, 0, stream>>>(x, Tb, NF / 4);
    k_wt<<<(K * 4096 + 255) / 256, 256, 0, stream>>>(W, Wt, K * 4096, K * 64);

    // Chebyshev recursion in bf16 storage: T1 = L T0; Tk = 2 L T_{k-1} - T_{k-2}
    for (int p = 1; p < K; ++p) {
        float scale = (p == 1) ? 1.f : 2.f;
        float beta  = (p == 1) ? 0.f : -1.f;
        const unsigned short* Tin  = Tb + (size_t)(p - 1) * NF;
        const unsigned short* Tm2  = Tb + (size_t)(p >= 2 ? p - 2 : 0) * NF;
        k_prop<<<(N * 64 + 255) / 256, 256, 0, stream>>>(
            Tin, Tm2, Tb + (size_t)p * NF, rowptr, edat, N, scale, beta);
    }

    if (K == 8)      k_gemm<16><<<1024, 256, 0, stream>>>(Tb, Wt, bias, out, N, NF);
    else if (K == 4) k_gemm<8><<<1024, 256, 0, stream>>>(Tb, Wt, bias, out, N, NF);
    else if (K == 2) k_gemm<4><<<1024, 256, 0, stream>>>(Tb, Wt, bias, out, N, NF);
    else if (K == 1) k_gemm<2><<<1024, 256, 0, stream>>>(Tb, Wt, bias, out, N, NF);
}

// Round 4
// 526.540 us; speedup vs baseline: 1.5287x; 1.1053x over previous
//
#include <hip/hip_runtime.h>
#include <hip/hip_bf16.h>

typedef __attribute__((ext_vector_type(8))) short s16x8;
typedef __attribute__((ext_vector_type(4))) float f32x4;

#define HC 48       // edge chunks (hist + scatter + csum)
#define RBH 6400    // hist bins per range (25.6 KB LDS -> 6 blocks/CU, 16 ranges)
#define RBS 3200    // scatter cursors per range (12.8 KB LDS -> 6 blocks/CU, 32 ranges)

static __device__ __forceinline__ unsigned short f2bf(float f) {
    unsigned int u = __float_as_uint(f);
    unsigned int r = (u + 0x7FFFu + ((u >> 16) & 1u)) >> 16;
    return (unsigned short)r;
}

// ---- partial histograms, zero global atomics ----
// grid = 2 jobs * HR * HC. job0: src -> deg partials, job1: dst -> cnt partials
// partials[(job*HC + c)*N + n]
__global__ __launch_bounds__(256) void k_hist(const int* __restrict__ eidx,
                                              int* __restrict__ partials,
                                              int N, int E, int HR) {
    __shared__ int h[RBH];
    int b = blockIdx.x;
    int job = b / (HR * HC);
    int rc = b % (HR * HC);
    int r = rc / HC, c = rc % HC;
    int lo = r * RBH;
    int nb = min(RBH, N - lo);
    if (nb <= 0) return;
    for (int i = threadIdx.x; i < nb; i += 256) h[i] = 0;
    __syncthreads();
    const int* vals = eidx + (size_t)job * E;
    int e0 = (int)((long long)E * c / HC);
    int e1 = (int)((long long)E * (c + 1) / HC);
    for (int e = e0 + threadIdx.x; e < e1; e += 256) {
        unsigned rel = (unsigned)(vals[e] - lo);
        if (rel < (unsigned)nb) atomicAdd(&h[rel], 1);
    }
    __syncthreads();
    int* outp = partials + ((size_t)(job * HC + c)) * N + lo;
    for (int i = threadIdx.x; i < nb; i += 256) outp[i] = h[i];
}

// ---- combine partials -> dis (rsqrt of src-degree) and cnt (dst histogram) ----
__global__ void k_reduce(const int* __restrict__ partials, float* __restrict__ dis,
                         int* __restrict__ cnt, int N) {
    int n = blockIdx.x * blockDim.x + threadIdx.x;
    if (n >= N) return;
    int dsum = 0, csum = 0;
    for (int c = 0; c < HC; ++c) {
        dsum += partials[(size_t)c * N + n];
        csum += partials[(size_t)(HC + c) * N + n];
    }
    dis[n] = dsum > 0 ? rsqrtf((float)dsum) : 0.f;
    cnt[n] = csum;
}

// ---- 3-kernel exclusive scan of cnt -> rowptr ----
__global__ void k_scan1(const int* __restrict__ cnt, int* __restrict__ incl,
                        int* __restrict__ bsum, int N) {
    __shared__ int sm[1024];
    int t = threadIdx.x;
    int i = blockIdx.x * 1024 + t;
    sm[t] = (i < N) ? cnt[i] : 0;
    __syncthreads();
    for (int off = 1; off < 1024; off <<= 1) {
        int add = (t >= off) ? sm[t - off] : 0;
        __syncthreads();
        sm[t] += add;
        __syncthreads();
    }
    if (i < N) incl[i] = sm[t];
    if (t == 1023) bsum[blockIdx.x] = sm[1023];
}

__global__ void k_scan2(const int* __restrict__ bsum, int* __restrict__ boff,
                        int nb, int* __restrict__ rowptr, int N) {
    if (threadIdx.x == 0 && blockIdx.x == 0) {
        int run = 0;
        for (int b = 0; b < nb; ++b) { boff[b] = run; run += bsum[b]; }
        rowptr[N] = run;
    }
}

__global__ void k_scan3(const int* __restrict__ cnt, const int* __restrict__ boff,
                        int* __restrict__ rowptr, int N) {
    int i = blockIdx.x * 1024 + threadIdx.x;
    if (i < N) rowptr[i] = rowptr[i] - cnt[i] + boff[blockIdx.x];  // inclusive -> exclusive
}

// ---- in-place 2D prefix over dst partials: pdst[c][n] -> rowptr[n] + sum_{c'<c} pdst[c'][n]
__global__ void k_csum(int* __restrict__ pdst, const int* __restrict__ rowptr, int N) {
    int n = blockIdx.x * blockDim.x + threadIdx.x;
    if (n >= N) return;
    int run = rowptr[n];
    for (int c = 0; c < HC; ++c) {
        size_t idx = (size_t)c * N + n;
        int t = pdst[idx];
        pdst[idx] = run;
        run += t;
    }
}

// ---- bucket edges by dst, LDS cursors only (no global atomics) ----
// grid = SR ranges * HC chunks; cursor bases precomputed by k_csum
__global__ __launch_bounds__(256) void k_scatter(
        const int* __restrict__ src, const int* __restrict__ dst,
        const float* __restrict__ dis, const int* __restrict__ cbase,
        int2* __restrict__ edat, int N, int E) {
    __shared__ int cur[RBS];
    int r = blockIdx.x / HC, c = blockIdx.x % HC;
    int lo = r * RBS;
    int nb = min(RBS, N - lo);
    if (nb <= 0) return;
    for (int i = threadIdx.x; i < nb; i += 256)
        cur[i] = cbase[(size_t)c * N + lo + i];
    __syncthreads();
    int e0 = (int)((long long)E * c / HC);
    int e1 = (int)((long long)E * (c + 1) / HC);
    for (int e = e0 + threadIdx.x; e < e1; e += 256) {
        int d = dst[e];
        unsigned rel = (unsigned)(d - lo);
        if (rel < (unsigned)nb) {
            int s = src[e];
            int p = atomicAdd(&cur[rel], 1);
            edat[p] = make_int2(s, __float_as_int(-dis[s] * dis[d]));
        }
    }
}

// ---- x -> bf16 copy (T_0) ----
__global__ void k_xb(const float* __restrict__ x, unsigned short* __restrict__ tb0, int n4) {
    int i = blockIdx.x * blockDim.x + threadIdx.x;
    if (i < n4) {
        float4 v = ((const float4*)x)[i];
        ushort4 o;
        o.x = f2bf(v.x); o.y = f2bf(v.y); o.z = f2bf(v.z); o.w = f2bf(v.w);
        ((ushort4*)tb0)[i] = o;
    }
}

// ---- W [K][64][64] fp32 -> Wt bf16 transposed (A-operand friendly) ----
__global__ void k_wt(const float* __restrict__ W, unsigned short* __restrict__ wt,
                     int total, int KI) {
    int t = blockIdx.x * blockDim.x + threadIdx.x;
    if (t < total) {
        float v = W[t];
        int k = t >> 12;
        int r = t & 4095;
        int i = r >> 6;
        int j = r & 63;
        wt[(size_t)j * KI + (k << 6) + i] = f2bf(v);
    }
}

// ---- one Chebyshev propagation, all-bf16 state:
//   Tout = scale*(L_hat @ Tin) + beta*Tm2   (compute fp32, storage bf16)
// one wave per dst node; group g=lane>>3 owns edge slot g (8 edges in flight),
// lane i=lane&7 owns feature octet i -> dwordx4 (16 B) gather, 128 B per row.
__global__ __launch_bounds__(256) void k_prop(
        const unsigned short* __restrict__ Tin,
        const unsigned short* __restrict__ Tm2,
        unsigned short* __restrict__ Tout,
        const int* __restrict__ rowptr, const int2* __restrict__ edat,
        int N, float scale, float beta) {
    int gt = blockIdx.x * blockDim.x + threadIdx.x;
    int wid = gt >> 6;
    if (wid >= N) return;
    int lane = gt & 63;
    int g = lane >> 3;      // edge slot
    int i = lane & 7;       // feature octet
    int rs = rowptr[wid], re = rowptr[wid + 1];
    float acc[8];
#pragma unroll
    for (int j = 0; j < 8; ++j) acc[j] = 0.f;
    for (int e = rs; e < re; e += 8) {
        int ee = e + g;
        bool live = ee < re;
        int2 ed = edat[live ? ee : re - 1];
        float w = live ? __int_as_float(ed.y) : 0.f;
        uint4 tv = *reinterpret_cast<const uint4*>(Tin + ((size_t)ed.x << 6) + (i << 3));
        acc[0] = fmaf(w, __uint_as_float(tv.x << 16), acc[0]);
        acc[1] = fmaf(w, __uint_as_float(tv.x & 0xffff0000u), acc[1]);
        acc[2] = fmaf(w, __uint_as_float(tv.y << 16), acc[2]);
        acc[3] = fmaf(w, __uint_as_float(tv.y & 0xffff0000u), acc[3]);
        acc[4] = fmaf(w, __uint_as_float(tv.z << 16), acc[4]);
        acc[5] = fmaf(w, __uint_as_float(tv.z & 0xffff0000u), acc[5]);
        acc[6] = fmaf(w, __uint_as_float(tv.w << 16), acc[6]);
        acc[7] = fmaf(w, __uint_as_float(tv.w & 0xffff0000u), acc[7]);
    }
#pragma unroll
    for (int m = 8; m <= 32; m <<= 1) {
#pragma unroll
        for (int j = 0; j < 8; ++j) acc[j] += __shfl_xor(acc[j], m);
    }
    if (g == 0) {
        size_t base = ((size_t)wid << 6) + (i << 3);
        float r[8];
#pragma unroll
        for (int j = 0; j < 8; ++j) r[j] = scale * acc[j];
        if (beta != 0.f) {
            uint4 pv = *reinterpret_cast<const uint4*>(Tm2 + base);
            r[0] = fmaf(beta, __uint_as_float(pv.x << 16), r[0]);
            r[1] = fmaf(beta, __uint_as_float(pv.x & 0xffff0000u), r[1]);
            r[2] = fmaf(beta, __uint_as_float(pv.y << 16), r[2]);
            r[3] = fmaf(beta, __uint_as_float(pv.y & 0xffff0000u), r[3]);
            r[4] = fmaf(beta, __uint_as_float(pv.z << 16), r[4]);
            r[5] = fmaf(beta, __uint_as_float(pv.z & 0xffff0000u), r[5]);
            r[6] = fmaf(beta, __uint_as_float(pv.w << 16), r[6]);
            r[7] = fmaf(beta, __uint_as_float(pv.w & 0xffff0000u), r[7]);
        }
        uint4 ov;
        ov.x = (unsigned)f2bf(r[0]) | ((unsigned)f2bf(r[1]) << 16);
        ov.y = (unsigned)f2bf(r[2]) | ((unsigned)f2bf(r[3]) << 16);
        ov.z = (unsigned)f2bf(r[4]) | ((unsigned)f2bf(r[5]) << 16);
        ov.w = (unsigned)f2bf(r[6]) | ((unsigned)f2bf(r[7]) << 16);
        *reinterpret_cast<uint4*>(Tout + base) = ov;
    }
}

// ---- out = relu( sum_k T_k @ W_k + bias ) via D = W^T . T^T (MFMA 16x16x32 bf16) ----
template <int KS>
__global__ __launch_bounds__(256) void k_gemm(const unsigned short* __restrict__ tb,
                                              const unsigned short* __restrict__ wt,
                                              const float* __restrict__ bias,
                                              float* __restrict__ out,
                                              int N, int NF) {
    int lane = threadIdx.x & 63;
    int w = threadIdx.x >> 6;
    int l16 = lane & 15;
    int quad = lane >> 4;
    const int KI = KS * 32;

    s16x8 afr[KS];
    {
        const unsigned short* wrow = wt + (size_t)(w * 16 + l16) * KI + quad * 8;
#pragma unroll
        for (int ks = 0; ks < KS; ++ks)
            afr[ks] = *reinterpret_cast<const s16x8*>(wrow + ks * 32);
    }
    f32x4 bias4 = *reinterpret_cast<const f32x4*>(bias + w * 16 + quad * 4);

    int ntiles = N >> 4;
    for (int t = blockIdx.x; t < ntiles; t += gridDim.x) {
        const unsigned short* bbase = tb + (size_t)(t * 16 + l16) * 64 + quad * 8;
        f32x4 acc = {0.f, 0.f, 0.f, 0.f};
#pragma unroll
        for (int ks = 0; ks < KS; ++ks) {
            s16x8 bf = *reinterpret_cast<const s16x8*>(
                bbase + (size_t)(ks >> 1) * NF + (ks & 1) * 32);
            acc = __builtin_amdgcn_mfma_f32_16x16x32_bf16(afr[ks], bf, acc, 0, 0, 0);
        }
        float* orow = out + (size_t)(t * 16 + l16) * 64 + w * 16 + quad * 4;
        f32x4 r;
#pragma unroll
        for (int q = 0; q < 4; ++q) {
            float v = acc[q] + bias4[q];
            r[q] = v > 0.f ? v : 0.f;
        }
        *reinterpret_cast<f32x4*>(orow) = r;
    }
}

extern "C" void kernel_launch(void* const* d_in, const int* in_sizes, int n_in,
                              void* d_out, int out_size, void* d_ws, size_t ws_size,
                              hipStream_t stream) {
    const float* x    = (const float*)d_in[0];
    const int*   eidx = (const int*)d_in[1];
    const float* W    = (const float*)d_in[2];
    const float* bias = (const float*)d_in[3];
    float* out = (float*)d_out;

    const int NF = in_sizes[0];       // N*64
    const int N  = NF / 64;
    const int E  = in_sizes[1] / 2;
    const int K  = in_sizes[2] / 4096;

    const int* src = eidx;
    const int* dst = eidx + E;

    // workspace (~150 MB)
    char* ws = (char*)d_ws;
    size_t off = 0;
    auto alloc = [&](size_t bytes) -> char* {
        char* p = ws + off;
        off = (off + bytes + 255) & ~(size_t)255;
        return p;
    };
    unsigned short* Tb = (unsigned short*)alloc((size_t)K * NF * 2);   // bf16 T_0..T_{K-1}
    unsigned short* Wt = (unsigned short*)alloc((size_t)64 * K * 64 * 2);
    int2*  edat   = (int2*)alloc((size_t)E * 8);
    int*   rowptr = (int*)alloc((size_t)(N + 1) * 4);
    int*   cnt    = (int*)alloc((size_t)N * 4);
    int*   partials = (int*)alloc((size_t)2 * HC * N * 4);
    float* dis  = (float*)alloc((size_t)N * 4);
    int*   bsum = (int*)alloc(1024);
    int*   boff = (int*)alloc(1024);
    (void)ws_size; (void)n_in; (void)out_size;

    int HR = (N + RBH - 1) / RBH;   // 16
    int SR = (N + RBS - 1) / RBS;   // 32
    int* pdst = partials + (size_t)HC * N;

    k_hist<<<2 * HR * HC, 256, 0, stream>>>(eidx, partials, N, E, HR);
    k_reduce<<<(N + 255) / 256, 256, 0, stream>>>(partials, dis, cnt, N);
    int nb = (N + 1023) / 1024;
    k_scan1<<<nb, 1024, 0, stream>>>(cnt, rowptr, bsum, N);
    k_scan2<<<1, 64, 0, stream>>>(bsum, boff, nb, rowptr, N);
    k_scan3<<<nb, 1024, 0, stream>>>(cnt, boff, rowptr, N);
    k_csum<<<(N + 255) / 256, 256, 0, stream>>>(pdst, rowptr, N);
    k_scatter<<<SR * HC, 256, 0, stream>>>(src, dst, dis, pdst, edat, N, E);
    k_xb<<<(NF / 4 + 255) / 256, 256, 0, stream>>>(x, Tb, NF / 4);
    k_wt<<<(K * 4096 + 255) / 256, 256, 0, stream>>>(W, Wt, K * 4096, K * 64);

    // Chebyshev recursion in bf16 storage: T1 = L T0; Tk = 2 L T_{k-1} - T_{k-2}
    for (int p = 1; p < K; ++p) {
        float scale = (p == 1) ? 1.f : 2.f;
        float beta  = (p == 1) ? 0.f : -1.f;
        const unsigned short* Tin  = Tb + (size_t)(p - 1) * NF;
        const unsigned short* Tm2  = Tb + (size_t)(p >= 2 ? p - 2 : 0) * NF;
        k_prop<<<(N * 64 + 255) / 256, 256, 0, stream>>>(
            Tin, Tm2, Tb + (size_t)p * NF, rowptr, edat, N, scale, beta);
    }

    if (K == 8)      k_gemm<16><<<1024, 256, 0, stream>>>(Tb, Wt, bias, out, N, NF);
    else if (K == 4) k_gemm<8><<<1024, 256, 0, stream>>>(Tb, Wt, bias, out, N, NF);
    else if (K == 2) k_gemm<4><<<1024, 256, 0, stream>>>(Tb, Wt, bias, out, N, NF);
    else if (K == 1) k_gemm<2><<<1024, 256, 0, stream>>>(Tb, Wt, bias, out, N, NF);
}

// Round 5
// 496.743 us; speedup vs baseline: 1.6204x; 1.0600x over previous
//
#include <hip/hip_runtime.h>
#include <hip/hip_bf16.h>

typedef __attribute__((ext_vector_type(8))) short s16x8;
typedef __attribute__((ext_vector_type(4))) float f32x4;

#define HC 48       // edge chunks (hist + scatter + csum)
#define RBH 6400    // hist bins per range (25.6 KB LDS, 16 ranges for N=100k)
#define RBS 3200    // scatter cursors per range (12.8 KB LDS, 32 ranges)

static __device__ __forceinline__ unsigned short f2bf(float f) {
    unsigned int u = __float_as_uint(f);
    unsigned int r = (u + 0x7FFFu + ((u >> 16) & 1u)) >> 16;
    return (unsigned short)r;
}

// ---- partial histograms, zero global atomics, int4 edge loads ----
// grid = 2 jobs * HR * HC. job0: src -> deg partials, job1: dst -> cnt partials
__global__ __launch_bounds__(256) void k_hist(const int* __restrict__ eidx,
                                              int* __restrict__ partials,
                                              int N, int E, int HR) {
    __shared__ int h[RBH];
    int b = blockIdx.x;
    int job = b / (HR * HC);
    int rc = b % (HR * HC);
    int r = rc / HC, c = rc % HC;
    int lo = r * RBH;
    int nb = min(RBH, N - lo);
    if (nb <= 0) return;
    for (int i = threadIdx.x; i < nb; i += 256) h[i] = 0;
    __syncthreads();
    const int* vals = eidx + (size_t)job * E;
    int e0 = (int)(((long long)E * c / HC) & ~3LL);
    int e1 = (c == HC - 1) ? E : (int)(((long long)E * (c + 1) / HC) & ~3LL);
    int e = e0 + threadIdx.x * 4;
    for (; e + 4 <= e1; e += 1024) {
        int4 v = *reinterpret_cast<const int4*>(vals + e);
        unsigned r0 = (unsigned)(v.x - lo), r1 = (unsigned)(v.y - lo);
        unsigned r2 = (unsigned)(v.z - lo), r3 = (unsigned)(v.w - lo);
        if (r0 < (unsigned)nb) atomicAdd(&h[r0], 1);
        if (r1 < (unsigned)nb) atomicAdd(&h[r1], 1);
        if (r2 < (unsigned)nb) atomicAdd(&h[r2], 1);
        if (r3 < (unsigned)nb) atomicAdd(&h[r3], 1);
    }
    if (threadIdx.x == 0)
        for (int t = e1 & ~3; t < e1; ++t) {
            unsigned rel = (unsigned)(vals[t] - lo);
            if (rel < (unsigned)nb) atomicAdd(&h[rel], 1);
        }
    __syncthreads();
    int* outp = partials + ((size_t)(job * HC + c)) * N + lo;
    for (int i = threadIdx.x; i < nb; i += 256) outp[i] = h[i];
}

// ---- combine partials -> dis (rsqrt of src-degree) and cnt (dst histogram) ----
__global__ void k_reduce(const int* __restrict__ partials, float* __restrict__ dis,
                         int* __restrict__ cnt, int N) {
    int n = blockIdx.x * blockDim.x + threadIdx.x;
    if (n >= N) return;
    int dsum = 0, csum = 0;
    for (int c = 0; c < HC; ++c) {
        dsum += partials[(size_t)c * N + n];
        csum += partials[(size_t)(HC + c) * N + n];
    }
    dis[n] = dsum > 0 ? rsqrtf((float)dsum) : 0.f;
    cnt[n] = csum;
}

// ---- 3-kernel exclusive scan of cnt -> rowptr ----
__global__ void k_scan1(const int* __restrict__ cnt, int* __restrict__ incl,
                        int* __restrict__ bsum, int N) {
    __shared__ int sm[1024];
    int t = threadIdx.x;
    int i = blockIdx.x * 1024 + t;
    sm[t] = (i < N) ? cnt[i] : 0;
    __syncthreads();
    for (int off = 1; off < 1024; off <<= 1) {
        int add = (t >= off) ? sm[t - off] : 0;
        __syncthreads();
        sm[t] += add;
        __syncthreads();
    }
    if (i < N) incl[i] = sm[t];
    if (t == 1023) bsum[blockIdx.x] = sm[1023];
}

__global__ void k_scan2(const int* __restrict__ bsum, int* __restrict__ boff,
                        int nb, int* __restrict__ rowptr, int N) {
    if (threadIdx.x == 0 && blockIdx.x == 0) {
        int run = 0;
        for (int b = 0; b < nb; ++b) { boff[b] = run; run += bsum[b]; }
        rowptr[N] = run;
    }
}

__global__ void k_scan3(const int* __restrict__ cnt, const int* __restrict__ boff,
                        int* __restrict__ rowptr, int N) {
    int i = blockIdx.x * 1024 + threadIdx.x;
    if (i < N) rowptr[i] = rowptr[i] - cnt[i] + boff[blockIdx.x];  // inclusive -> exclusive
}

// ---- in-place 2D prefix over dst partials: pdst[c][n] -> rowptr[n] + sum_{c'<c} pdst[c'][n]
__global__ void k_csum(int* __restrict__ pdst, const int* __restrict__ rowptr, int N) {
    int n = blockIdx.x * blockDim.x + threadIdx.x;
    if (n >= N) return;
    int run = rowptr[n];
    for (int c = 0; c < HC; ++c) {
        size_t idx = (size_t)c * N + n;
        int t = pdst[idx];
        pdst[idx] = run;
        run += t;
    }
}

// ---- bucket edges by dst: srcs[p] = src (4 B payload, LDS cursors, int4 loads) ----
__global__ __launch_bounds__(256) void k_scatter(
        const int* __restrict__ src, const int* __restrict__ dst,
        const int* __restrict__ cbase, int* __restrict__ srcs, int N, int E) {
    __shared__ int cur[RBS];
    int r = blockIdx.x / HC, c = blockIdx.x % HC;
    int lo = r * RBS;
    int nb = min(RBS, N - lo);
    if (nb <= 0) return;
    for (int i = threadIdx.x; i < nb; i += 256)
        cur[i] = cbase[(size_t)c * N + lo + i];
    __syncthreads();
    int e0 = (int)(((long long)E * c / HC) & ~3LL);
    int e1 = (c == HC - 1) ? E : (int)(((long long)E * (c + 1) / HC) & ~3LL);
    int e = e0 + threadIdx.x * 4;
    for (; e + 4 <= e1; e += 1024) {
        int4 d4 = *reinterpret_cast<const int4*>(dst + e);
        unsigned r0 = (unsigned)(d4.x - lo), r1 = (unsigned)(d4.y - lo);
        unsigned r2 = (unsigned)(d4.z - lo), r3 = (unsigned)(d4.w - lo);
        if (r0 < (unsigned)nb) srcs[atomicAdd(&cur[r0], 1)] = src[e];
        if (r1 < (unsigned)nb) srcs[atomicAdd(&cur[r1], 1)] = src[e + 1];
        if (r2 < (unsigned)nb) srcs[atomicAdd(&cur[r2], 1)] = src[e + 2];
        if (r3 < (unsigned)nb) srcs[atomicAdd(&cur[r3], 1)] = src[e + 3];
    }
    if (threadIdx.x == 0)
        for (int t = e1 & ~3; t < e1; ++t) {
            unsigned rel = (unsigned)(dst[t] - lo);
            if (rel < (unsigned)nb) srcs[atomicAdd(&cur[rel], 1)] = src[t];
        }
}

// ---- T0 = bf16(x); Ys0 = bf16(dis*x); zero pad row N of both Ys buffers ----
__global__ void k_ys0(const float* __restrict__ x, const float* __restrict__ dis,
                      unsigned short* __restrict__ tb0, unsigned short* __restrict__ ysA,
                      unsigned short* __restrict__ ysB, int N) {
    int t = blockIdx.x * blockDim.x + threadIdx.x;
    if (t >= (N + 1) * 32) return;
    int row = t >> 5, p = t & 31;
    size_t o = ((size_t)row << 6) + (p << 1);
    if (row == N) {
        *(unsigned*)(ysA + o) = 0;
        *(unsigned*)(ysB + o) = 0;
        return;
    }
    float2 v = *reinterpret_cast<const float2*>(x + o);
    float dv = dis[row];
    *(unsigned*)(tb0 + o) = (unsigned)f2bf(v.x) | ((unsigned)f2bf(v.y) << 16);
    *(unsigned*)(ysA + o) = (unsigned)f2bf(v.x * dv) | ((unsigned)f2bf(v.y * dv) << 16);
}

// ---- W [K][64][64] fp32 -> Wt bf16 transposed (A-operand friendly) ----
__global__ void k_wt(const float* __restrict__ W, unsigned short* __restrict__ wt,
                     int total, int KI) {
    int t = blockIdx.x * blockDim.x + threadIdx.x;
    if (t < total) {
        float v = W[t];
        int k = t >> 12;
        int r = t & 4095;
        int i = r >> 6;
        int j = r & 63;
        wt[(size_t)j * KI + (k << 6) + i] = f2bf(v);
    }
}

// ---- one Chebyshev propagation with pre-scaled gathers:
//   A[d]    = sum_{s in N(d)} Ysin[s]              (unweighted row-sum!)
//   Tout[d] = -scale*dis[d]*A[d] + beta*Tm2[d]
//   Ysout[d]= dis[d]*Tout[d]
// one wave per node; g=lane>>3 = edge slot, i=lane&7 = feature octet (b128 gather).
// 16 edges in flight per iteration; dead slots gather the zeroed pad row N (L1-hot).
__global__ __launch_bounds__(256) void k_prop(
        const unsigned short* __restrict__ Ysin,
        const unsigned short* __restrict__ Tm2,
        unsigned short* __restrict__ Tout,
        unsigned short* __restrict__ Ysout,
        const int* __restrict__ rowptr, const int* __restrict__ srcs,
        const float* __restrict__ dis,
        int N, float scale, float beta) {
    int gt = blockIdx.x * blockDim.x + threadIdx.x;
    int wid = gt >> 6;
    if (wid >= N) return;
    int lane = gt & 63;
    int g = lane >> 3;      // edge slot 0..7
    int i = lane & 7;       // feature octet
    int rs = rowptr[wid], re = rowptr[wid + 1];
    float acc[8];
#pragma unroll
    for (int j = 0; j < 8; ++j) acc[j] = 0.f;
    for (int e = rs; e < re; e += 16) {
        int ee0 = e + g, ee1 = ee0 + 8;
        int s0 = srcs[min(ee0, re - 1)];
        int s1 = srcs[min(ee1, re - 1)];
        if (ee0 >= re) s0 = N;          // pad row (zeros)
        if (ee1 >= re) s1 = N;
        uint4 t0 = *reinterpret_cast<const uint4*>(Ysin + ((size_t)s0 << 6) + (i << 3));
        uint4 t1 = *reinterpret_cast<const uint4*>(Ysin + ((size_t)s1 << 6) + (i << 3));
        acc[0] += __uint_as_float(t0.x << 16);
        acc[1] += __uint_as_float(t0.x & 0xffff0000u);
        acc[2] += __uint_as_float(t0.y << 16);
        acc[3] += __uint_as_float(t0.y & 0xffff0000u);
        acc[4] += __uint_as_float(t0.z << 16);
        acc[5] += __uint_as_float(t0.z & 0xffff0000u);
        acc[6] += __uint_as_float(t0.w << 16);
        acc[7] += __uint_as_float(t0.w & 0xffff0000u);
        acc[0] += __uint_as_float(t1.x << 16);
        acc[1] += __uint_as_float(t1.x & 0xffff0000u);
        acc[2] += __uint_as_float(t1.y << 16);
        acc[3] += __uint_as_float(t1.y & 0xffff0000u);
        acc[4] += __uint_as_float(t1.z << 16);
        acc[5] += __uint_as_float(t1.z & 0xffff0000u);
        acc[6] += __uint_as_float(t1.w << 16);
        acc[7] += __uint_as_float(t1.w & 0xffff0000u);
    }
#pragma unroll
    for (int m = 8; m <= 32; m <<= 1) {
#pragma unroll
        for (int j = 0; j < 8; ++j) acc[j] += __shfl_xor(acc[j], m);
    }
    if (g == 0) {
        float dv = dis[wid];
        float sc = -scale * dv;
        size_t base = ((size_t)wid << 6) + (i << 3);
        float r[8];
#pragma unroll
        for (int j = 0; j < 8; ++j) r[j] = sc * acc[j];
        if (beta != 0.f) {
            uint4 pv = *reinterpret_cast<const uint4*>(Tm2 + base);
            r[0] = fmaf(beta, __uint_as_float(pv.x << 16), r[0]);
            r[1] = fmaf(beta, __uint_as_float(pv.x & 0xffff0000u), r[1]);
            r[2] = fmaf(beta, __uint_as_float(pv.y << 16), r[2]);
            r[3] = fmaf(beta, __uint_as_float(pv.y & 0xffff0000u), r[3]);
            r[4] = fmaf(beta, __uint_as_float(pv.z << 16), r[4]);
            r[5] = fmaf(beta, __uint_as_float(pv.z & 0xffff0000u), r[5]);
            r[6] = fmaf(beta, __uint_as_float(pv.w << 16), r[6]);
            r[7] = fmaf(beta, __uint_as_float(pv.w & 0xffff0000u), r[7]);
        }
        uint4 ov, yv;
        ov.x = (unsigned)f2bf(r[0]) | ((unsigned)f2bf(r[1]) << 16);
        ov.y = (unsigned)f2bf(r[2]) | ((unsigned)f2bf(r[3]) << 16);
        ov.z = (unsigned)f2bf(r[4]) | ((unsigned)f2bf(r[5]) << 16);
        ov.w = (unsigned)f2bf(r[6]) | ((unsigned)f2bf(r[7]) << 16);
        yv.x = (unsigned)f2bf(r[0] * dv) | ((unsigned)f2bf(r[1] * dv) << 16);
        yv.y = (unsigned)f2bf(r[2] * dv) | ((unsigned)f2bf(r[3] * dv) << 16);
        yv.z = (unsigned)f2bf(r[4] * dv) | ((unsigned)f2bf(r[5] * dv) << 16);
        yv.w = (unsigned)f2bf(r[6] * dv) | ((unsigned)f2bf(r[7] * dv) << 16);
        *reinterpret_cast<uint4*>(Tout + base) = ov;
        *reinterpret_cast<uint4*>(Ysout + base) = yv;
    }
}

// ---- out = relu( sum_k T_k @ W_k + bias ) via D = W^T . T^T (MFMA 16x16x32 bf16) ----
template <int KS>
__global__ __launch_bounds__(256) void k_gemm(const unsigned short* __restrict__ tb,
                                              const unsigned short* __restrict__ wt,
                                              const float* __restrict__ bias,
                                              float* __restrict__ out,
                                              int N, int NF) {
    int lane = threadIdx.x & 63;
    int w = threadIdx.x >> 6;
    int l16 = lane & 15;
    int quad = lane >> 4;
    const int KI = KS * 32;

    s16x8 afr[KS];
    {
        const unsigned short* wrow = wt + (size_t)(w * 16 + l16) * KI + quad * 8;
#pragma unroll
        for (int ks = 0; ks < KS; ++ks)
            afr[ks] = *reinterpret_cast<const s16x8*>(wrow + ks * 32);
    }
    f32x4 bias4 = *reinterpret_cast<const f32x4*>(bias + w * 16 + quad * 4);

    int ntiles = N >> 4;
    for (int t = blockIdx.x; t < ntiles; t += gridDim.x) {
        const unsigned short* bbase = tb + (size_t)(t * 16 + l16) * 64 + quad * 8;
        f32x4 acc = {0.f, 0.f, 0.f, 0.f};
#pragma unroll
        for (int ks = 0; ks < KS; ++ks) {
            s16x8 bf = *reinterpret_cast<const s16x8*>(
                bbase + (size_t)(ks >> 1) * NF + (ks & 1) * 32);
            acc = __builtin_amdgcn_mfma_f32_16x16x32_bf16(afr[ks], bf, acc, 0, 0, 0);
        }
        float* orow = out + (size_t)(t * 16 + l16) * 64 + w * 16 + quad * 4;
        f32x4 r;
#pragma unroll
        for (int q = 0; q < 4; ++q) {
            float v = acc[q] + bias4[q];
            r[q] = v > 0.f ? v : 0.f;
        }
        *reinterpret_cast<f32x4*>(orow) = r;
    }
}

extern "C" void kernel_launch(void* const* d_in, const int* in_sizes, int n_in,
                              void* d_out, int out_size, void* d_ws, size_t ws_size,
                              hipStream_t stream) {
    const float* x    = (const float*)d_in[0];
    const int*   eidx = (const int*)d_in[1];
    const float* W    = (const float*)d_in[2];
    const float* bias = (const float*)d_in[3];
    float* out = (float*)d_out;

    const int NF = in_sizes[0];       // N*64
    const int N  = NF / 64;
    const int E  = in_sizes[1] / 2;
    const int K  = in_sizes[2] / 4096;

    const int* src = eidx;
    const int* dst = eidx + E;

    // workspace (~175 MB)
    char* ws = (char*)d_ws;
    size_t off = 0;
    auto alloc = [&](size_t bytes) -> char* {
        char* p = ws + off;
        off = (off + bytes + 255) & ~(size_t)255;
        return p;
    };
    unsigned short* Tb = (unsigned short*)alloc((size_t)K * NF * 2);       // bf16 T_0..T_{K-1}
    unsigned short* Ys[2];
    Ys[0] = (unsigned short*)alloc((size_t)(N + 1) * 64 * 2);              // pre-scaled (ping)
    Ys[1] = (unsigned short*)alloc((size_t)(N + 1) * 64 * 2);              // pre-scaled (pong)
    unsigned short* Wt = (unsigned short*)alloc((size_t)64 * K * 64 * 2);
    int*   srcs   = (int*)alloc((size_t)E * 4);
    int*   rowptr = (int*)alloc((size_t)(N + 1) * 4);
    int*   cnt    = (int*)alloc((size_t)N * 4);
    int*   partials = (int*)alloc((size_t)2 * HC * N * 4);
    float* dis  = (float*)alloc((size_t)N * 4);
    int*   bsum = (int*)alloc(1024);
    int*   boff = (int*)alloc(1024);
    (void)ws_size; (void)n_in; (void)out_size;

    int HR = (N + RBH - 1) / RBH;   // 16
    int SR = (N + RBS - 1) / RBS;   // 32
    int* pdst = partials + (size_t)HC * N;

    k_hist<<<2 * HR * HC, 256, 0, stream>>>(eidx, partials, N, E, HR);
    k_reduce<<<(N + 255) / 256, 256, 0, stream>>>(partials, dis, cnt, N);
    int nb = (N + 1023) / 1024;
    k_scan1<<<nb, 1024, 0, stream>>>(cnt, rowptr, bsum, N);
    k_scan2<<<1, 64, 0, stream>>>(bsum, boff, nb, rowptr, N);
    k_scan3<<<nb, 1024, 0, stream>>>(cnt, boff, rowptr, N);
    k_csum<<<(N + 255) / 256, 256, 0, stream>>>(pdst, rowptr, N);
    k_scatter<<<SR * HC, 256, 0, stream>>>(src, dst, pdst, srcs, N, E);
    k_ys0<<<((N + 1) * 32 + 255) / 256, 256, 0, stream>>>(x, dis, Tb, Ys[0], Ys[1], N);
    k_wt<<<(K * 4096 + 255) / 256, 256, 0, stream>>>(W, Wt, K * 4096, K * 64);

    // Chebyshev recursion: T1 = L T0; Tk = 2 L T_{k-1} - T_{k-2}  (Ys pre-scaled)
    for (int p = 1; p < K; ++p) {
        float scale = (p == 1) ? 1.f : 2.f;
        float beta  = (p == 1) ? 0.f : -1.f;
        const unsigned short* Tm2 = Tb + (size_t)(p >= 2 ? p - 2 : 0) * NF;
        k_prop<<<(N * 64 + 255) / 256, 256, 0, stream>>>(
            Ys[(p - 1) & 1], Tm2, Tb + (size_t)p * NF, Ys[p & 1],
            rowptr, srcs, dis, N, scale, beta);
    }

    if (K == 8)      k_gemm<16><<<1024, 256, 0, stream>>>(Tb, Wt, bias, out, N, NF);
    else if (K == 4) k_gemm<8><<<1024, 256, 0, stream>>>(Tb, Wt, bias, out, N, NF);
    else if (K == 2) k_gemm<4><<<1024, 256, 0, stream>>>(Tb, Wt, bias, out, N, NF);
    else if (K == 1) k_gemm<2><<<1024, 256, 0, stream>>>(Tb, Wt, bias, out, N, NF);
}